// Round 11
// baseline (325.228 us; speedup 1.0000x reference)
//
#include <hip/hip_runtime.h>
#include <math.h>

#define F_IN 128
#define HID  64
#define NH   4
#define DD   16
#define CC   16
#define CSTE 1e-5f

typedef _Float16 h2     __attribute__((ext_vector_type(2)));
typedef float    f2     __attribute__((ext_vector_type(2)));
typedef short    short8 __attribute__((ext_vector_type(8)));
typedef float    f4v    __attribute__((ext_vector_type(4)));

// LDS strides (elements) — padded so b128 frag reads are ≤2-way bank conflicts
#define WIT_LD 136
#define W2T_LD 72
#define H_LD   72

__device__ __forceinline__ unsigned short bf16r(float f) {
    unsigned int u = __builtin_bit_cast(unsigned int, f);
    unsigned int r = (u + 0x7FFFu + ((u >> 16) & 1u)) >> 16;
    return (unsigned short)r;
}

// ---------------- fp8 scalar helpers (OCP e4m3 via hw cvt) ----------------
__device__ __forceinline__ float fp8_to_f32(unsigned int b) {
    f2 v = __builtin_amdgcn_cvt_pk_f32_fp8((int)b, false);
    return v.x;
}
__device__ __forceinline__ f2 fp8x2_to_f32(unsigned int w) {   // {lo, hi} in one op
    return __builtin_amdgcn_cvt_pk_f32_fp8((int)w, false);
}
__device__ __forceinline__ unsigned char f32_to_fp8(float f) {
    int w = __builtin_amdgcn_cvt_pk_fp8_f32(f, f, 0, false);
    return (unsigned char)(w & 0xff);
}

// ---------------- fp4 e2m1 helpers ----------------
__device__ __forceinline__ float fp4_dec1(unsigned int n) {
    unsigned int e = (n >> 1) & 3u, m = n & 1u;
    float mag = (e == 0) ? 0.5f * (float)m
                         : (float)(1u << (e - 1)) * (1.0f + 0.5f * (float)m);
    return (n & 8u) ? -mag : mag;
}
__device__ __forceinline__ unsigned int fp4_enc1(float f) {
    unsigned int s = (f < 0.f) ? 8u : 0u;
    float a = fabsf(f);
    unsigned int m;
    if      (a < 0.25f) m = 0u;
    else if (a < 0.75f) m = 1u;
    else if (a < 1.25f) m = 2u;
    else if (a < 1.75f) m = 3u;
    else if (a < 2.5f)  m = 4u;
    else if (a < 3.5f)  m = 5u;
    else if (a < 5.0f)  m = 6u;
    else                m = 7u;
    return s | m;
}

#if __has_builtin(__builtin_amdgcn_cvt_scalef32_pk_f32_fp4) && __has_builtin(__builtin_amdgcn_cvt_scalef32_pk_fp4_f32)
#define HAS_FP4 1
#endif

__device__ __forceinline__ void fp4x16_dec(uint2 w, float* v) {
#ifdef HAS_FP4
    f2 r;
    r = __builtin_amdgcn_cvt_scalef32_pk_f32_fp4(w.x, 1.0f, 0); v[0]  = r.x; v[1]  = r.y;
    r = __builtin_amdgcn_cvt_scalef32_pk_f32_fp4(w.x, 1.0f, 1); v[2]  = r.x; v[3]  = r.y;
    r = __builtin_amdgcn_cvt_scalef32_pk_f32_fp4(w.x, 1.0f, 2); v[4]  = r.x; v[5]  = r.y;
    r = __builtin_amdgcn_cvt_scalef32_pk_f32_fp4(w.x, 1.0f, 3); v[6]  = r.x; v[7]  = r.y;
    r = __builtin_amdgcn_cvt_scalef32_pk_f32_fp4(w.y, 1.0f, 0); v[8]  = r.x; v[9]  = r.y;
    r = __builtin_amdgcn_cvt_scalef32_pk_f32_fp4(w.y, 1.0f, 1); v[10] = r.x; v[11] = r.y;
    r = __builtin_amdgcn_cvt_scalef32_pk_f32_fp4(w.y, 1.0f, 2); v[12] = r.x; v[13] = r.y;
    r = __builtin_amdgcn_cvt_scalef32_pk_f32_fp4(w.y, 1.0f, 3); v[14] = r.x; v[15] = r.y;
#else
    #pragma unroll
    for (int j = 0; j < 8; ++j) {
        v[j]     = fp4_dec1((w.x >> (4 * j)) & 0xFu);
        v[8 + j] = fp4_dec1((w.y >> (4 * j)) & 0xFu);
    }
#endif
}

__device__ __forceinline__ uint2 fp4x16_enc(const float* v) {
#ifdef HAS_FP4
    unsigned int a = 0u, b = 0u;
    a = __builtin_amdgcn_cvt_scalef32_pk_fp4_f32(a, v[0],  v[1],  1.0f, 0);
    a = __builtin_amdgcn_cvt_scalef32_pk_fp4_f32(a, v[2],  v[3],  1.0f, 1);
    a = __builtin_amdgcn_cvt_scalef32_pk_fp4_f32(a, v[4],  v[5],  1.0f, 2);
    a = __builtin_amdgcn_cvt_scalef32_pk_fp4_f32(a, v[6],  v[7],  1.0f, 3);
    b = __builtin_amdgcn_cvt_scalef32_pk_fp4_f32(b, v[8],  v[9],  1.0f, 0);
    b = __builtin_amdgcn_cvt_scalef32_pk_fp4_f32(b, v[10], v[11], 1.0f, 1);
    b = __builtin_amdgcn_cvt_scalef32_pk_fp4_f32(b, v[12], v[13], 1.0f, 2);
    b = __builtin_amdgcn_cvt_scalef32_pk_fp4_f32(b, v[14], v[15], 1.0f, 3);
    return {a, b};
#else
    unsigned int a = 0u, b = 0u;
    #pragma unroll
    for (int j = 0; j < 8; ++j) {
        a |= fp4_enc1(v[j])     << (4 * j);
        b |= fp4_enc1(v[8 + j]) << (4 * j);
    }
    return {a, b};
#endif
}

// store one M row: per-row fp8 scale (s8), fp4 payload, K packed with scale
__device__ __forceinline__ void store_m_row(
    uint2* __restrict__ Mout, unsigned short* __restrict__ SKout,
    int node, int lane, const float* u, float kacc)
{
    float rm = 0.f;
    #pragma unroll
    for (int j = 0; j < 16; ++j) rm = fmaxf(rm, fabsf(u[j]));
    unsigned char s8 = f32_to_fp8(rm * (1.0f / 6.0f));
    float se = fp8_to_f32((unsigned int)s8);
    float invs = (se > 0.f) ? (1.0f / se) : 0.f;
    float tq[16];
    #pragma unroll
    for (int j = 0; j < 16; ++j) tq[j] = u[j] * invs;
    Mout[(size_t)node * 64 + lane] = fp4x16_enc(tq);
    SKout[(size_t)node * 64 + lane] =
        (unsigned short)((unsigned short)s8 | ((unsigned short)f32_to_fp8(kacc) << 8));
}

// per-hop gamma (hop>=1): hopwise[hop] * softmax_over_heads(temp[:,hop])[h]
__device__ __forceinline__ float gamma_for(const float* __restrict__ temp,
                                           const float* __restrict__ hopwise,
                                           int h, int hop) {
    float t0 = temp[0 * 4 + hop], t1 = temp[1 * 4 + hop];
    float t2 = temp[2 * 4 + hop], t3 = temp[3 * 4 + hop];
    float mx = fmaxf(fmaxf(t0, t1), fmaxf(t2, t3));
    float e0 = __expf(t0 - mx), e1 = __expf(t1 - mx);
    float e2 = __expf(t2 - mx), e3 = __expf(t3 - mx);
    float ssum = e0 + e1 + e2 + e3;
    float eh = (h == 0) ? e0 : (h == 1) ? e1 : (h == 2) ? e2 : e3;
    return hopwise[hop] * eh / ssum;
}

// reduce-scatter over the 16 lanes of a head: u[j] holds column j (natural);
// afterwards lane p holds, in u[0], the group sum for column p.
__device__ __forceinline__ void reduce_scatter16(float* u, int p) {
    #pragma unroll
    for (int k = 0; k < 4; ++k) {
        const int m = 1 << k;
        bool bit = (p >> k) & 1;
        const int n = 8 >> k;
        #pragma unroll
        for (int j = 0; j < n; ++j) {
            float give = bit ? u[2 * j]     : u[2 * j + 1];
            float keep = bit ? u[2 * j + 1] : u[2 * j];
            float got  = __shfl_xor(give, m, 64);
            u[j] = keep + got;
        }
    }
}

// den = sum over the 16-lane group of qd*kacc, plus CST
__device__ __forceinline__ float den16(float qd, float kacc) {
    float kq = qd * kacc;
    kq += __shfl_xor(kq, 1, 64);
    kq += __shfl_xor(kq, 2, 64);
    kq += __shfl_xor(kq, 4, 64);
    kq += __shfl_xor(kq, 8, 64);
    return kq + CSTE;
}

// ---------------- CSR scan ----------------
__global__ __launch_bounds__(1024) void scan_a(const int* __restrict__ deg,
                                               int* __restrict__ offsets,
                                               int* __restrict__ bsum, int N) {
    __shared__ int wsum[16], woff[16];
    int lane = threadIdx.x & 63, w = threadIdx.x >> 6;
    int i0 = blockIdx.x * 4096 + (int)threadIdx.x * 4;
    int d0 = (i0 + 0 < N) ? deg[i0 + 0] : 0;
    int d1 = (i0 + 1 < N) ? deg[i0 + 1] : 0;
    int d2 = (i0 + 2 < N) ? deg[i0 + 2] : 0;
    int d3 = (i0 + 3 < N) ? deg[i0 + 3] : 0;
    int tsum = d0 + d1 + d2 + d3;
    int incl = tsum;
    #pragma unroll
    for (int m = 1; m < 64; m <<= 1) {
        int t = __shfl_up(incl, m, 64);
        if (lane >= m) incl += t;
    }
    if (lane == 63) wsum[w] = incl;
    __syncthreads();
    if (threadIdx.x == 0) {
        int r = 0;
        for (int k = 0; k < 16; ++k) { int t = wsum[k]; woff[k] = r; r += t; }
        bsum[blockIdx.x] = r;
    }
    __syncthreads();
    int excl = woff[w] + incl - tsum;
    if (i0 + 0 < N) offsets[i0 + 0] = excl;
    if (i0 + 1 < N) offsets[i0 + 1] = excl + d0;
    if (i0 + 2 < N) offsets[i0 + 2] = excl + d0 + d1;
    if (i0 + 3 < N) offsets[i0 + 3] = excl + d0 + d1 + d2;
}

__global__ void scan_c(int* __restrict__ offsets, const int* __restrict__ bsum,
                       int nb, int N) {
    int i = blockIdx.x * blockDim.x + threadIdx.x;
    if (i < N) {
        int bkt = i >> 12;
        int base = 0;
        for (int b = 0; b < bkt; ++b) base += bsum[b];
        offsets[i] += base;
    }
    if (i == 0) {
        int tot = 0;
        for (int b = 0; b < nb; ++b) tot += bsum[b];
        offsets[N] = tot;
    }
}

__global__ void scatter_kernel(const int* __restrict__ ei, const int* __restrict__ offsets,
                               int* __restrict__ cursor, int* __restrict__ csr, int E) {
    int e = blockIdx.x * blockDim.x + threadIdx.x;
    if (e < E) {
        int src = ei[e];
        int dst = ei[E + e];
        int pos = atomicAdd(&cursor[dst], 1);
        csr[offsets[dst] + pos] = src;
    }
}

// ---------------- fused MFMA QKV + edge counting ----------------
// blocks [0, qb): qkv (64 nodes/block); blocks [qb, qb+eb): degree count
__global__ __launch_bounds__(256) void qkv_count(
    const float* __restrict__ x,
    const float* __restrict__ Wi, const float* __restrict__ bi,
    const float* __restrict__ Wq, const float* __restrict__ bq,
    const float* __restrict__ Wk, const float* __restrict__ bk,
    const float* __restrict__ Wv, const float* __restrict__ bv,
    const float* __restrict__ temp,
    float* __restrict__ Q, unsigned char* __restrict__ K0,
    _Float16* __restrict__ Vh, float* __restrict__ hidden,
    const int* __restrict__ ei, int* __restrict__ deg,
    int E, int qb, int N)
{
    __shared__ unsigned short wit[64 * WIT_LD];
    __shared__ unsigned short w2t[192 * W2T_LD];
    __shared__ unsigned short hlds[64 * H_LD];
    if ((int)blockIdx.x >= qb) {
        int e = ((int)blockIdx.x - qb) * 256 + (int)threadIdx.x;
        if (e < E) atomicAdd(&deg[ei[E + e]], 1);   // dst = ei[1][e]
        return;
    }
    int t = threadIdx.x;
    #pragma unroll
    for (int i = 0; i < 32; ++i) {
        int g = t + i * 256;                       // 8192 = 128*64
        wit[(g & 63) * WIT_LD + (g >> 6)] = bf16r(Wi[g]);
    }
    #pragma unroll
    for (int i = 0; i < 16; ++i) {
        int g = t + i * 256;                       // 4096 = 64*64
        int k = g >> 6, n = g & 63;
        w2t[(n      ) * W2T_LD + k] = bf16r(Wq[g]);
        w2t[(n +  64) * W2T_LD + k] = bf16r(Wk[g]);
        w2t[(n + 128) * W2T_LD + k] = bf16r(Wv[g]);
    }
    __syncthreads();

    int lane = t & 63, w = t >> 6;
    int p = lane & 15, quad = lane >> 4;
    int mbase = blockIdx.x * 64 + w * 16;

    // ---- stage 1: h = relu(x@Wi + bi) ----
    short8 afrag[4];
    {
        int node = mbase + p;
        if (node >= N) node = N - 1;               // clamped read; stores guarded
        const float* xr = x + (size_t)node * F_IN + quad * 8;
        #pragma unroll
        for (int ks = 0; ks < 4; ++ks) {
            float4 a0 = *(const float4*)(xr + ks * 32);
            float4 a1 = *(const float4*)(xr + ks * 32 + 4);
            short8 f;
            f[0] = bf16r(a0.x); f[1] = bf16r(a0.y); f[2] = bf16r(a0.z); f[3] = bf16r(a0.w);
            f[4] = bf16r(a1.x); f[5] = bf16r(a1.y); f[6] = bf16r(a1.z); f[7] = bf16r(a1.w);
            afrag[ks] = f;
        }
    }
    #pragma unroll
    for (int nt = 0; nt < 4; ++nt) {
        f4v acc = {0.f, 0.f, 0.f, 0.f};
        #pragma unroll
        for (int ks = 0; ks < 4; ++ks) {
            short8 b = *(const short8*)&wit[(nt * 16 + p) * WIT_LD + ks * 32 + quad * 8];
            acc = __builtin_amdgcn_mfma_f32_16x16x32_bf16(afrag[ks], b, acc, 0, 0, 0);
        }
        float bb = bi[nt * 16 + p];
        #pragma unroll
        for (int r = 0; r < 4; ++r) {
            float hv = fmaxf(acc[r] + bb, 0.f);
            hlds[(w * 16 + quad * 4 + r) * H_LD + nt * 16 + p] = bf16r(hv);
        }
    }
    __syncthreads();

    // ---- stage 2: [Q|K|V] = h @ W2 + b ----
    short8 ha0 = *(const short8*)&hlds[(w * 16 + p) * H_LD + quad * 8];
    short8 ha1 = *(const short8*)&hlds[(w * 16 + p) * H_LD + 32 + quad * 8];
    int node_r = mbase + quad * 4;
    #pragma unroll
    for (int nt = 0; nt < 12; ++nt) {
        f4v acc = {0.f, 0.f, 0.f, 0.f};
        short8 b0 = *(const short8*)&w2t[(nt * 16 + p) * W2T_LD + quad * 8];
        short8 b1 = *(const short8*)&w2t[(nt * 16 + p) * W2T_LD + 32 + quad * 8];
        acc = __builtin_amdgcn_mfma_f32_16x16x32_bf16(ha0, b0, acc, 0, 0, 0);
        acc = __builtin_amdgcn_mfma_f32_16x16x32_bf16(ha1, b1, acc, 0, 0, 0);
        int col = nt * 16 + p;
        #pragma unroll
        for (int r = 0; r < 4; ++r) {
            int node = node_r + r;
            if (node >= N) continue;
            float v = acc[r];
            if (col < 64) {
                v += bq[col];
                Q[(size_t)node * 64 + col] = (v > 0.f) ? (1.f + v) : __expf(v);
            } else if (col < 128) {
                int c = col - 64;
                v += bk[c];
                float kv = (v > 0.f) ? (1.f + v) : __expf(v);
                K0[(size_t)node * 64 + c] = f32_to_fp8(kv);
            } else {
                int c = col - 128;
                v += bv[c];
                Vh[(size_t)node * 64 + c] = (_Float16)v;
                hidden[(size_t)node * 64 + c] = v * temp[(c >> 4) * 4];  // hop-0 gamma
            }
        }
    }
}

// M layout: per node 64 uint2 (512 fp4 payload), NATURAL columns:
// lane (h*16+p), nibble j holds M[h][d=p][c=j] / scale.  SK[n][lane] = {scale fp8, K fp8}.

// ---------------- hop 1: M1 = A (K ⊗ V) fp4+scale, K1 in SK1 ----------------
__global__ __launch_bounds__(256) void hop1_all(
    const float* __restrict__ Q, const unsigned char* __restrict__ K0,
    const _Float16* __restrict__ Vh,
    const int* __restrict__ offsets, const int* __restrict__ csr,
    const float* __restrict__ temp, const float* __restrict__ hopwise,
    uint2* __restrict__ M1, unsigned short* __restrict__ SK1,
    float* __restrict__ hidden, int N)
{
    int lane = threadIdx.x & 63;
    int node = blockIdx.x * 4 + (threadIdx.x >> 6);
    if (node >= N) return;
    int h = lane >> 4;
    float gh = gamma_for(temp, hopwise, h, 1);
    h2 u16[8];
    #pragma unroll
    for (int j = 0; j < 8; ++j) u16[j] = h2{(_Float16)0.f, (_Float16)0.f};
    float kacc = 0.f;
    int beg = offsets[node], end = offsets[node + 1];
    int t = beg;
    for (; t + 1 < end; t += 2) {
        int s0 = csr[t], s1 = csr[t + 1];
        const uint4* v0p = (const uint4*)(Vh + (size_t)s0 * 64 + h * 16);
        const uint4* v1p = (const uint4*)(Vh + (size_t)s1 * 64 + h * 16);
        uint4 a0 = v0p[0], a1 = v0p[1];
        uint4 b0 = v1p[0], b1 = v1p[1];
        float k0 = fp8_to_f32(K0[(size_t)s0 * 64 + lane]);
        float k1 = fp8_to_f32(K0[(size_t)s1 * 64 + lane]);
        kacc += k0 + k1;
        _Float16 k0h = (_Float16)k0, k1h = (_Float16)k1;
        h2 k02 = {k0h, k0h}, k12 = {k1h, k1h};
        const unsigned int aw[8] = {a0.x, a0.y, a0.z, a0.w, a1.x, a1.y, a1.z, a1.w};
        const unsigned int bw[8] = {b0.x, b0.y, b0.z, b0.w, b1.x, b1.y, b1.z, b1.w};
        #pragma unroll
        for (int j = 0; j < 8; ++j) {
            u16[j] += k02 * __builtin_bit_cast(h2, aw[j]);
            u16[j] += k12 * __builtin_bit_cast(h2, bw[j]);
        }
    }
    for (; t < end; ++t) {
        int s = csr[t];
        const uint4* vp = (const uint4*)(Vh + (size_t)s * 64 + h * 16);
        uint4 a0 = vp[0], a1 = vp[1];
        float kk = fp8_to_f32(K0[(size_t)s * 64 + lane]);
        kacc += kk;
        _Float16 kh = (_Float16)kk;
        h2 k2 = {kh, kh};
        const unsigned int aw[8] = {a0.x, a0.y, a0.z, a0.w, a1.x, a1.y, a1.z, a1.w};
        #pragma unroll
        for (int j = 0; j < 8; ++j)
            u16[j] += k2 * __builtin_bit_cast(h2, aw[j]);
    }
    float u[16];
    #pragma unroll
    for (int j = 0; j < 8; ++j) { u[2 * j] = (float)u16[j].x; u[2 * j + 1] = (float)u16[j].y; }
    store_m_row(M1, SK1, node, lane, u, kacc);
    float qd = Q[(size_t)node * 64 + lane];
    #pragma unroll
    for (int j = 0; j < 16; ++j) u[j] *= qd;
    reduce_scatter16(u, lane & 15);
    float g = gh / den16(qd, kacc);
    hidden[(size_t)node * 64 + lane] += g * u[0];
}

// ---------------- hop 2: fp4 M gather, store M2, update hidden ----------------
__global__ __launch_bounds__(256) void hop2_all(
    const float* __restrict__ Q, const uint2* __restrict__ Mprev,
    const unsigned short* __restrict__ SKprev,
    const int* __restrict__ offsets, const int* __restrict__ csr,
    const float* __restrict__ temp, const float* __restrict__ hopwise,
    uint2* __restrict__ Mnext, unsigned short* __restrict__ SKnext,
    float* __restrict__ hidden, int N)
{
    int lane = threadIdx.x & 63;
    int node = blockIdx.x * 4 + (threadIdx.x >> 6);
    if (node >= N) return;
    float gh = gamma_for(temp, hopwise, lane >> 4, 2);
    const uint2* Mb = Mprev + lane;
    const unsigned short* SKb = SKprev + lane;
    float u[16];
    #pragma unroll
    for (int j = 0; j < 16; ++j) u[j] = 0.f;
    float kacc = 0.f;
    int beg = offsets[node], end = offsets[node + 1];
    int t = beg;
    for (; t + 3 < end; t += 4) {
        int s0 = csr[t], s1 = csr[t + 1], s2 = csr[t + 2], s3 = csr[t + 3];
        uint2 w0 = Mb[(size_t)s0 * 64];
        uint2 w1 = Mb[(size_t)s1 * 64];
        uint2 w2 = Mb[(size_t)s2 * 64];
        uint2 w3 = Mb[(size_t)s3 * 64];
        f2 sk0 = fp8x2_to_f32(SKb[(size_t)s0 * 64]);
        f2 sk1 = fp8x2_to_f32(SKb[(size_t)s1 * 64]);
        f2 sk2 = fp8x2_to_f32(SKb[(size_t)s2 * 64]);
        f2 sk3 = fp8x2_to_f32(SKb[(size_t)s3 * 64]);
        kacc += (sk0.y + sk1.y) + (sk2.y + sk3.y);
        float v[16];
        fp4x16_dec(w0, v);
        #pragma unroll
        for (int j = 0; j < 16; ++j) u[j] = fmaf(sk0.x, v[j], u[j]);
        fp4x16_dec(w1, v);
        #pragma unroll
        for (int j = 0; j < 16; ++j) u[j] = fmaf(sk1.x, v[j], u[j]);
        fp4x16_dec(w2, v);
        #pragma unroll
        for (int j = 0; j < 16; ++j) u[j] = fmaf(sk2.x, v[j], u[j]);
        fp4x16_dec(w3, v);
        #pragma unroll
        for (int j = 0; j < 16; ++j) u[j] = fmaf(sk3.x, v[j], u[j]);
    }
    for (; t < end; ++t) {
        int sn = csr[t];
        uint2 w = Mb[(size_t)sn * 64];
        f2 sk = fp8x2_to_f32(SKb[(size_t)sn * 64]);
        kacc += sk.y;
        float v[16];
        fp4x16_dec(w, v);
        #pragma unroll
        for (int j = 0; j < 16; ++j) u[j] = fmaf(sk.x, v[j], u[j]);
    }
    store_m_row(Mnext, SKnext, node, lane, u, kacc);
    float qd = Q[(size_t)node * 64 + lane];
    #pragma unroll
    for (int j = 0; j < 16; ++j) u[j] *= qd;
    reduce_scatter16(u, lane & 15);
    float g = gh / den16(qd, kacc);
    hidden[(size_t)node * 64 + lane] += g * u[0];
}

// ---------------- hop 3 + fused output projection ----------------
__global__ __launch_bounds__(256) void hop3_out(
    const float* __restrict__ Q, const uint2* __restrict__ Mprev,
    const unsigned short* __restrict__ SKprev,
    const int* __restrict__ offsets, const int* __restrict__ csr,
    const float* __restrict__ temp, const float* __restrict__ hopwise,
    const float* __restrict__ hidden, const float* __restrict__ Wo,
    const float* __restrict__ bo, float* __restrict__ out, int N)
{
    int lane = threadIdx.x & 63;
    int node = blockIdx.x * 4 + (threadIdx.x >> 6);
    if (node >= N) return;
    float gh = gamma_for(temp, hopwise, lane >> 4, 3);
    // Wo row for this lane (16 floats) + bias
    float wor[16];
    {
        const float4* wp = (const float4*)(Wo + lane * 16);
        float4 a = wp[0], b = wp[1], c = wp[2], d = wp[3];
        wor[0] = a.x; wor[1] = a.y; wor[2]  = a.z; wor[3]  = a.w;
        wor[4] = b.x; wor[5] = b.y; wor[6]  = b.z; wor[7]  = b.w;
        wor[8] = c.x; wor[9] = c.y; wor[10] = c.z; wor[11] = c.w;
        wor[12] = d.x; wor[13] = d.y; wor[14] = d.z; wor[15] = d.w;
    }
    float bov = bo[lane & 15];
    const uint2* Mb = Mprev + lane;
    const unsigned short* SKb = SKprev + lane;
    float u[16];
    #pragma unroll
    for (int j = 0; j < 16; ++j) u[j] = 0.f;
    float kacc = 0.f;
    int beg = offsets[node], end = offsets[node + 1];
    int t = beg;
    for (; t + 3 < end; t += 4) {
        int s0 = csr[t], s1 = csr[t + 1], s2 = csr[t + 2], s3 = csr[t + 3];
        uint2 w0 = Mb[(size_t)s0 * 64];
        uint2 w1 = Mb[(size_t)s1 * 64];
        uint2 w2 = Mb[(size_t)s2 * 64];
        uint2 w3 = Mb[(size_t)s3 * 64];
        f2 sk0 = fp8x2_to_f32(SKb[(size_t)s0 * 64]);
        f2 sk1 = fp8x2_to_f32(SKb[(size_t)s1 * 64]);
        f2 sk2 = fp8x2_to_f32(SKb[(size_t)s2 * 64]);
        f2 sk3 = fp8x2_to_f32(SKb[(size_t)s3 * 64]);
        kacc += (sk0.y + sk1.y) + (sk2.y + sk3.y);
        float v[16];
        fp4x16_dec(w0, v);
        #pragma unroll
        for (int j = 0; j < 16; ++j) u[j] = fmaf(sk0.x, v[j], u[j]);
        fp4x16_dec(w1, v);
        #pragma unroll
        for (int j = 0; j < 16; ++j) u[j] = fmaf(sk1.x, v[j], u[j]);
        fp4x16_dec(w2, v);
        #pragma unroll
        for (int j = 0; j < 16; ++j) u[j] = fmaf(sk2.x, v[j], u[j]);
        fp4x16_dec(w3, v);
        #pragma unroll
        for (int j = 0; j < 16; ++j) u[j] = fmaf(sk3.x, v[j], u[j]);
    }
    for (; t < end; ++t) {
        int sn = csr[t];
        uint2 w = Mb[(size_t)sn * 64];
        f2 sk = fp8x2_to_f32(SKb[(size_t)sn * 64]);
        kacc += sk.y;
        float v[16];
        fp4x16_dec(w, v);
        #pragma unroll
        for (int j = 0; j < 16; ++j) u[j] = fmaf(sk.x, v[j], u[j]);
    }
    float qd = Q[(size_t)node * 64 + lane];
    #pragma unroll
    for (int j = 0; j < 16; ++j) u[j] *= qd;
    reduce_scatter16(u, lane & 15);
    float g = gh / den16(qd, kacc);
    float hval = hidden[(size_t)node * 64 + lane] + g * u[0];
    // out[n][c] = sum_l hval_l * Wo[l][c] + bo[c]
    float o[16];
    #pragma unroll
    for (int c = 0; c < 16; ++c) o[c] = hval * wor[c];
    reduce_scatter16(o, lane & 15);
    float tot = o[0];
    tot += __shfl_xor(tot, 16, 64);
    tot += __shfl_xor(tot, 32, 64);
    if (lane < 16) out[(size_t)node * 16 + lane] = tot + bov;
}

extern "C" void kernel_launch(void* const* d_in, const int* in_sizes, int n_in,
                              void* d_out, int out_size, void* d_ws, size_t ws_size,
                              hipStream_t stream) {
    const float* x       = (const float*)d_in[0];
    const int*   ei      = (const int*)  d_in[1];
    const float* Wi      = (const float*)d_in[2];
    const float* bi      = (const float*)d_in[3];
    const float* Wq      = (const float*)d_in[4];
    const float* bq      = (const float*)d_in[5];
    const float* Wk      = (const float*)d_in[6];
    const float* bk      = (const float*)d_in[7];
    const float* Wv      = (const float*)d_in[8];
    const float* bv      = (const float*)d_in[9];
    const float* Wo      = (const float*)d_in[10];
    const float* bo      = (const float*)d_in[11];
    const float* hopwise = (const float*)d_in[12];
    const float* temp    = (const float*)d_in[13];

    const int N = in_sizes[0] / F_IN;
    const int E = in_sizes[1] / 2;

    char* ws = (char*)d_ws;
    size_t off = 0;
    auto take = [&](size_t bytes) -> char* {
        char* p = ws + off;
        off += (bytes + 255) & ~(size_t)255;
        return p;
    };
    float*          Q      = (float*)take((size_t)N * 64 * 4);
    _Float16*       Vh     = (_Float16*)take((size_t)N * 64 * 2);
    float*          hidden = (float*)take((size_t)N * 64 * 4);
    unsigned char*  K0     = (unsigned char*)take((size_t)N * 64);
    unsigned short* SK1    = (unsigned short*)take((size_t)N * 64 * 2);
    unsigned short* SK2    = (unsigned short*)take((size_t)N * 64 * 2);
    int*            degcur = (int*)take((size_t)2 * N * 4);   // deg | cursor
    int*            offs   = (int*)take((size_t)(N + 1) * 4);
    int*            csr    = (int*)take((size_t)E * 4);
    int             nb     = (N + 4095) / 4096;
    int*            bsum   = (int*)take((size_t)nb * 4);
    uint2*          M1     = (uint2*)take((size_t)N * 512);
    uint2*          M2     = (uint2*)take((size_t)N * 512);

    int* deg    = degcur;
    int* cursor = degcur + N;

    hipMemsetAsync(degcur, 0, (size_t)2 * N * 4, stream);

    int eb = (E + 255) / 256;
    int qb = (N + 63) / 64;
    // fused: qkv (qb blocks) + degree count (eb blocks)
    qkv_count<<<qb + eb, 256, 0, stream>>>(x, Wi, bi, Wq, bq, Wk, bk, Wv, bv,
                                           temp, Q, K0, Vh, hidden,
                                           ei, deg, E, qb, N);
    scan_a<<<nb, 1024, 0, stream>>>(deg, offs, bsum, N);
    scan_c<<<(N + 255) / 256, 256, 0, stream>>>(offs, bsum, nb, N);
    scatter_kernel<<<eb, 256, 0, stream>>>(ei, offs, cursor, csr, E);

    int nb4 = (N + 3) / 4;
    hop1_all<<<nb4, 256, 0, stream>>>(Q, K0, Vh, offs, csr, temp, hopwise,
                                      M1, SK1, hidden, N);
    hop2_all<<<nb4, 256, 0, stream>>>(Q, M1, SK1, offs, csr, temp, hopwise,
                                      M2, SK2, hidden, N);
    hop3_out<<<nb4, 256, 0, stream>>>(Q, M2, SK2, offs, csr, temp, hopwise,
                                      hidden, Wo, bo, (float*)d_out, N);
}

// Round 12
// 309.534 us; speedup vs baseline: 1.0507x; 1.0507x over previous
//
#include <hip/hip_runtime.h>
#include <math.h>

#define F_IN 128
#define HID  64
#define NH   4
#define DD   16
#define CC   16
#define CSTE 1e-5f

typedef _Float16 h2     __attribute__((ext_vector_type(2)));
typedef float    f2     __attribute__((ext_vector_type(2)));
typedef short    short8 __attribute__((ext_vector_type(8)));
typedef float    f4v    __attribute__((ext_vector_type(4)));

// LDS strides (elements) — padded so b128 frag reads are ≤2-way bank conflicts
#define WIT_LD 136
#define W2T_LD 72
#define H_LD   72

__device__ __forceinline__ unsigned short bf16r(float f) {
    unsigned int u = __builtin_bit_cast(unsigned int, f);
    unsigned int r = (u + 0x7FFFu + ((u >> 16) & 1u)) >> 16;
    return (unsigned short)r;
}

// ---------------- fp8 scalar helpers (OCP e4m3 via hw cvt) ----------------
__device__ __forceinline__ float fp8_to_f32(unsigned int b) {
    f2 v = __builtin_amdgcn_cvt_pk_f32_fp8((int)b, false);
    return v.x;
}
__device__ __forceinline__ f2 fp8x2_to_f32(unsigned int w) {   // {lo, hi} in one op
    return __builtin_amdgcn_cvt_pk_f32_fp8((int)w, false);
}
__device__ __forceinline__ unsigned char f32_to_fp8(float f) {
    int w = __builtin_amdgcn_cvt_pk_fp8_f32(f, f, 0, false);
    return (unsigned char)(w & 0xff);
}

// ---------------- fp4 e2m1 helpers ----------------
__device__ __forceinline__ float fp4_dec1(unsigned int n) {
    unsigned int e = (n >> 1) & 3u, m = n & 1u;
    float mag = (e == 0) ? 0.5f * (float)m
                         : (float)(1u << (e - 1)) * (1.0f + 0.5f * (float)m);
    return (n & 8u) ? -mag : mag;
}
__device__ __forceinline__ unsigned int fp4_enc1(float f) {
    unsigned int s = (f < 0.f) ? 8u : 0u;
    float a = fabsf(f);
    unsigned int m;
    if      (a < 0.25f) m = 0u;
    else if (a < 0.75f) m = 1u;
    else if (a < 1.25f) m = 2u;
    else if (a < 1.75f) m = 3u;
    else if (a < 2.5f)  m = 4u;
    else if (a < 3.5f)  m = 5u;
    else if (a < 5.0f)  m = 6u;
    else                m = 7u;
    return s | m;
}

#if __has_builtin(__builtin_amdgcn_cvt_scalef32_pk_f32_fp4) && __has_builtin(__builtin_amdgcn_cvt_scalef32_pk_fp4_f32)
#define HAS_FP4 1
#endif

__device__ __forceinline__ void fp4x16_dec(uint2 w, float* v) {
#ifdef HAS_FP4
    f2 r;
    r = __builtin_amdgcn_cvt_scalef32_pk_f32_fp4(w.x, 1.0f, 0); v[0]  = r.x; v[1]  = r.y;
    r = __builtin_amdgcn_cvt_scalef32_pk_f32_fp4(w.x, 1.0f, 1); v[2]  = r.x; v[3]  = r.y;
    r = __builtin_amdgcn_cvt_scalef32_pk_f32_fp4(w.x, 1.0f, 2); v[4]  = r.x; v[5]  = r.y;
    r = __builtin_amdgcn_cvt_scalef32_pk_f32_fp4(w.x, 1.0f, 3); v[6]  = r.x; v[7]  = r.y;
    r = __builtin_amdgcn_cvt_scalef32_pk_f32_fp4(w.y, 1.0f, 0); v[8]  = r.x; v[9]  = r.y;
    r = __builtin_amdgcn_cvt_scalef32_pk_f32_fp4(w.y, 1.0f, 1); v[10] = r.x; v[11] = r.y;
    r = __builtin_amdgcn_cvt_scalef32_pk_f32_fp4(w.y, 1.0f, 2); v[12] = r.x; v[13] = r.y;
    r = __builtin_amdgcn_cvt_scalef32_pk_f32_fp4(w.y, 1.0f, 3); v[14] = r.x; v[15] = r.y;
#else
    #pragma unroll
    for (int j = 0; j < 8; ++j) {
        v[j]     = fp4_dec1((w.x >> (4 * j)) & 0xFu);
        v[8 + j] = fp4_dec1((w.y >> (4 * j)) & 0xFu);
    }
#endif
}

__device__ __forceinline__ uint2 fp4x16_enc(const float* v) {
#ifdef HAS_FP4
    unsigned int a = 0u, b = 0u;
    a = __builtin_amdgcn_cvt_scalef32_pk_fp4_f32(a, v[0],  v[1],  1.0f, 0);
    a = __builtin_amdgcn_cvt_scalef32_pk_fp4_f32(a, v[2],  v[3],  1.0f, 1);
    a = __builtin_amdgcn_cvt_scalef32_pk_fp4_f32(a, v[4],  v[5],  1.0f, 2);
    a = __builtin_amdgcn_cvt_scalef32_pk_fp4_f32(a, v[6],  v[7],  1.0f, 3);
    b = __builtin_amdgcn_cvt_scalef32_pk_fp4_f32(b, v[8],  v[9],  1.0f, 0);
    b = __builtin_amdgcn_cvt_scalef32_pk_fp4_f32(b, v[10], v[11], 1.0f, 1);
    b = __builtin_amdgcn_cvt_scalef32_pk_fp4_f32(b, v[12], v[13], 1.0f, 2);
    b = __builtin_amdgcn_cvt_scalef32_pk_fp4_f32(b, v[14], v[15], 1.0f, 3);
    return {a, b};
#else
    unsigned int a = 0u, b = 0u;
    #pragma unroll
    for (int j = 0; j < 8; ++j) {
        a |= fp4_enc1(v[j])     << (4 * j);
        b |= fp4_enc1(v[8 + j]) << (4 * j);
    }
    return {a, b};
#endif
}

// store one M row: per-row fp8 scale (s8), fp4 payload, K packed with scale
__device__ __forceinline__ void store_m_row(
    uint2* __restrict__ Mout, unsigned short* __restrict__ SKout,
    int node, int lane, const float* u, float kacc)
{
    float rm = 0.f;
    #pragma unroll
    for (int j = 0; j < 16; ++j) rm = fmaxf(rm, fabsf(u[j]));
    unsigned char s8 = f32_to_fp8(rm * (1.0f / 6.0f));
    float se = fp8_to_f32((unsigned int)s8);
    float invs = (se > 0.f) ? (1.0f / se) : 0.f;
    float tq[16];
    #pragma unroll
    for (int j = 0; j < 16; ++j) tq[j] = u[j] * invs;
    Mout[(size_t)node * 64 + lane] = fp4x16_enc(tq);
    SKout[(size_t)node * 64 + lane] =
        (unsigned short)((unsigned short)s8 | ((unsigned short)f32_to_fp8(kacc) << 8));
}

// per-hop gamma (hop>=1): hopwise[hop] * softmax_over_heads(temp[:,hop])[h]
__device__ __forceinline__ float gamma_for(const float* __restrict__ temp,
                                           const float* __restrict__ hopwise,
                                           int h, int hop) {
    float t0 = temp[0 * 4 + hop], t1 = temp[1 * 4 + hop];
    float t2 = temp[2 * 4 + hop], t3 = temp[3 * 4 + hop];
    float mx = fmaxf(fmaxf(t0, t1), fmaxf(t2, t3));
    float e0 = __expf(t0 - mx), e1 = __expf(t1 - mx);
    float e2 = __expf(t2 - mx), e3 = __expf(t3 - mx);
    float ssum = e0 + e1 + e2 + e3;
    float eh = (h == 0) ? e0 : (h == 1) ? e1 : (h == 2) ? e2 : e3;
    return hopwise[hop] * eh / ssum;
}

// reduce-scatter over the 16 lanes of a head: u[j] holds column j (natural);
// afterwards lane p holds, in u[0], the group sum for column p.
__device__ __forceinline__ void reduce_scatter16(float* u, int p) {
    #pragma unroll
    for (int k = 0; k < 4; ++k) {
        const int m = 1 << k;
        bool bit = (p >> k) & 1;
        const int n = 8 >> k;
        #pragma unroll
        for (int j = 0; j < n; ++j) {
            float give = bit ? u[2 * j]     : u[2 * j + 1];
            float keep = bit ? u[2 * j + 1] : u[2 * j];
            float got  = __shfl_xor(give, m, 64);
            u[j] = keep + got;
        }
    }
}

// den = sum over the 16-lane group of qd*kacc, plus CST
__device__ __forceinline__ float den16(float qd, float kacc) {
    float kq = qd * kacc;
    kq += __shfl_xor(kq, 1, 64);
    kq += __shfl_xor(kq, 2, 64);
    kq += __shfl_xor(kq, 4, 64);
    kq += __shfl_xor(kq, 8, 64);
    return kq + CSTE;
}

// ---------------- CSR scan ----------------
__global__ __launch_bounds__(1024) void scan_a(const int* __restrict__ deg,
                                               int* __restrict__ offsets,
                                               int* __restrict__ bsum, int N) {
    __shared__ int wsum[16], woff[16];
    int lane = threadIdx.x & 63, w = threadIdx.x >> 6;
    int i0 = blockIdx.x * 4096 + (int)threadIdx.x * 4;
    int d0 = (i0 + 0 < N) ? deg[i0 + 0] : 0;
    int d1 = (i0 + 1 < N) ? deg[i0 + 1] : 0;
    int d2 = (i0 + 2 < N) ? deg[i0 + 2] : 0;
    int d3 = (i0 + 3 < N) ? deg[i0 + 3] : 0;
    int tsum = d0 + d1 + d2 + d3;
    int incl = tsum;
    #pragma unroll
    for (int m = 1; m < 64; m <<= 1) {
        int t = __shfl_up(incl, m, 64);
        if (lane >= m) incl += t;
    }
    if (lane == 63) wsum[w] = incl;
    __syncthreads();
    if (threadIdx.x == 0) {
        int r = 0;
        for (int k = 0; k < 16; ++k) { int t = wsum[k]; woff[k] = r; r += t; }
        bsum[blockIdx.x] = r;
    }
    __syncthreads();
    int excl = woff[w] + incl - tsum;
    if (i0 + 0 < N) offsets[i0 + 0] = excl;
    if (i0 + 1 < N) offsets[i0 + 1] = excl + d0;
    if (i0 + 2 < N) offsets[i0 + 2] = excl + d0 + d1;
    if (i0 + 3 < N) offsets[i0 + 3] = excl + d0 + d1 + d2;
}

__global__ void scan_c(int* __restrict__ offsets, const int* __restrict__ bsum,
                       int nb, int N) {
    int i = blockIdx.x * blockDim.x + threadIdx.x;
    if (i < N) {
        int bkt = i >> 12;
        int base = 0;
        for (int b = 0; b < bkt; ++b) base += bsum[b];
        offsets[i] += base;
    }
    if (i == 0) {
        int tot = 0;
        for (int b = 0; b < nb; ++b) tot += bsum[b];
        offsets[N] = tot;
    }
}

__global__ void scatter_kernel(const int* __restrict__ ei, const int* __restrict__ offsets,
                               int* __restrict__ cursor, int* __restrict__ csr, int E) {
    int e = blockIdx.x * blockDim.x + threadIdx.x;
    if (e < E) {
        int src = ei[e];
        int dst = ei[E + e];
        int pos = atomicAdd(&cursor[dst], 1);
        csr[offsets[dst] + pos] = src;
    }
}

// ---------------- fused MFMA QKV + edge counting ----------------
// blocks [0, qb): qkv (64 nodes/block); blocks [qb, qb+eb): degree count
__global__ __launch_bounds__(256) void qkv_count(
    const float* __restrict__ x,
    const float* __restrict__ Wi, const float* __restrict__ bi,
    const float* __restrict__ Wq, const float* __restrict__ bq,
    const float* __restrict__ Wk, const float* __restrict__ bk,
    const float* __restrict__ Wv, const float* __restrict__ bv,
    const float* __restrict__ temp,
    float* __restrict__ Q, unsigned char* __restrict__ K0,
    _Float16* __restrict__ Vh, float* __restrict__ hidden,
    const int* __restrict__ ei, int* __restrict__ deg,
    int E, int qb, int N)
{
    __shared__ unsigned short wit[64 * WIT_LD];
    __shared__ unsigned short w2t[192 * W2T_LD];
    __shared__ unsigned short hlds[64 * H_LD];
    if ((int)blockIdx.x >= qb) {
        int e = ((int)blockIdx.x - qb) * 256 + (int)threadIdx.x;
        if (e < E) atomicAdd(&deg[ei[E + e]], 1);   // dst = ei[1][e]
        return;
    }
    int t = threadIdx.x;
    #pragma unroll
    for (int i = 0; i < 32; ++i) {
        int g = t + i * 256;                       // 8192 = 128*64
        wit[(g & 63) * WIT_LD + (g >> 6)] = bf16r(Wi[g]);
    }
    #pragma unroll
    for (int i = 0; i < 16; ++i) {
        int g = t + i * 256;                       // 4096 = 64*64
        int k = g >> 6, n = g & 63;
        w2t[(n      ) * W2T_LD + k] = bf16r(Wq[g]);
        w2t[(n +  64) * W2T_LD + k] = bf16r(Wk[g]);
        w2t[(n + 128) * W2T_LD + k] = bf16r(Wv[g]);
    }
    __syncthreads();

    int lane = t & 63, w = t >> 6;
    int p = lane & 15, quad = lane >> 4;
    int mbase = blockIdx.x * 64 + w * 16;

    // ---- stage 1: h = relu(x@Wi + bi) ----
    short8 afrag[4];
    {
        int node = mbase + p;
        if (node >= N) node = N - 1;               // clamped read; stores guarded
        const float* xr = x + (size_t)node * F_IN + quad * 8;
        #pragma unroll
        for (int ks = 0; ks < 4; ++ks) {
            float4 a0 = *(const float4*)(xr + ks * 32);
            float4 a1 = *(const float4*)(xr + ks * 32 + 4);
            short8 f;
            f[0] = bf16r(a0.x); f[1] = bf16r(a0.y); f[2] = bf16r(a0.z); f[3] = bf16r(a0.w);
            f[4] = bf16r(a1.x); f[5] = bf16r(a1.y); f[6] = bf16r(a1.z); f[7] = bf16r(a1.w);
            afrag[ks] = f;
        }
    }
    #pragma unroll
    for (int nt = 0; nt < 4; ++nt) {
        f4v acc = {0.f, 0.f, 0.f, 0.f};
        #pragma unroll
        for (int ks = 0; ks < 4; ++ks) {
            short8 b = *(const short8*)&wit[(nt * 16 + p) * WIT_LD + ks * 32 + quad * 8];
            acc = __builtin_amdgcn_mfma_f32_16x16x32_bf16(afrag[ks], b, acc, 0, 0, 0);
        }
        float bb = bi[nt * 16 + p];
        #pragma unroll
        for (int r = 0; r < 4; ++r) {
            float hv = fmaxf(acc[r] + bb, 0.f);
            hlds[(w * 16 + quad * 4 + r) * H_LD + nt * 16 + p] = bf16r(hv);
        }
    }
    __syncthreads();

    // ---- stage 2: [Q|K|V] = h @ W2 + b ----
    short8 ha0 = *(const short8*)&hlds[(w * 16 + p) * H_LD + quad * 8];
    short8 ha1 = *(const short8*)&hlds[(w * 16 + p) * H_LD + 32 + quad * 8];
    int node_r = mbase + quad * 4;
    #pragma unroll
    for (int nt = 0; nt < 12; ++nt) {
        f4v acc = {0.f, 0.f, 0.f, 0.f};
        short8 b0 = *(const short8*)&w2t[(nt * 16 + p) * W2T_LD + quad * 8];
        short8 b1 = *(const short8*)&w2t[(nt * 16 + p) * W2T_LD + 32 + quad * 8];
        acc = __builtin_amdgcn_mfma_f32_16x16x32_bf16(ha0, b0, acc, 0, 0, 0);
        acc = __builtin_amdgcn_mfma_f32_16x16x32_bf16(ha1, b1, acc, 0, 0, 0);
        int col = nt * 16 + p;
        #pragma unroll
        for (int r = 0; r < 4; ++r) {
            int node = node_r + r;
            if (node >= N) continue;
            float v = acc[r];
            if (col < 64) {
                v += bq[col];
                Q[(size_t)node * 64 + col] = (v > 0.f) ? (1.f + v) : __expf(v);
            } else if (col < 128) {
                int c = col - 64;
                v += bk[c];
                float kv = (v > 0.f) ? (1.f + v) : __expf(v);
                K0[(size_t)node * 64 + c] = f32_to_fp8(kv);
            } else {
                int c = col - 128;
                v += bv[c];
                Vh[(size_t)node * 64 + c] = (_Float16)v;
                hidden[(size_t)node * 64 + c] = v * temp[(c >> 4) * 4];  // hop-0 gamma
            }
        }
    }
}

// M layout: per node 64 uint2 (512 fp4 payload), NATURAL columns:
// lane (h*16+p), nibble j holds M[h][d=p][c=j] / scale.  SK[n][lane] = {scale fp8, K fp8}.

// ---------------- hop 1: M1 = A (K ⊗ V) fp4+scale, K1 in SK1 ----------------
__global__ __launch_bounds__(256) void hop1_all(
    const float* __restrict__ Q, const unsigned char* __restrict__ K0,
    const _Float16* __restrict__ Vh,
    const int* __restrict__ offsets, const int* __restrict__ csr,
    const float* __restrict__ temp, const float* __restrict__ hopwise,
    uint2* __restrict__ M1, unsigned short* __restrict__ SK1,
    float* __restrict__ hidden, int N)
{
    int lane = threadIdx.x & 63;
    int node = blockIdx.x * 4 + (threadIdx.x >> 6);
    if (node >= N) return;
    int h = lane >> 4;
    float gh = gamma_for(temp, hopwise, h, 1);
    h2 u16[8];
    #pragma unroll
    for (int j = 0; j < 8; ++j) u16[j] = h2{(_Float16)0.f, (_Float16)0.f};
    float kacc = 0.f;
    int beg = offsets[node], end = offsets[node + 1];
    int t = beg;
    for (; t + 1 < end; t += 2) {
        int s0 = csr[t], s1 = csr[t + 1];
        const uint4* v0p = (const uint4*)(Vh + (size_t)s0 * 64 + h * 16);
        const uint4* v1p = (const uint4*)(Vh + (size_t)s1 * 64 + h * 16);
        uint4 a0 = v0p[0], a1 = v0p[1];
        uint4 b0 = v1p[0], b1 = v1p[1];
        float k0 = fp8_to_f32(K0[(size_t)s0 * 64 + lane]);
        float k1 = fp8_to_f32(K0[(size_t)s1 * 64 + lane]);
        kacc += k0 + k1;
        _Float16 k0h = (_Float16)k0, k1h = (_Float16)k1;
        h2 k02 = {k0h, k0h}, k12 = {k1h, k1h};
        const unsigned int aw[8] = {a0.x, a0.y, a0.z, a0.w, a1.x, a1.y, a1.z, a1.w};
        const unsigned int bw[8] = {b0.x, b0.y, b0.z, b0.w, b1.x, b1.y, b1.z, b1.w};
        #pragma unroll
        for (int j = 0; j < 8; ++j) {
            u16[j] += k02 * __builtin_bit_cast(h2, aw[j]);
            u16[j] += k12 * __builtin_bit_cast(h2, bw[j]);
        }
    }
    for (; t < end; ++t) {
        int s = csr[t];
        const uint4* vp = (const uint4*)(Vh + (size_t)s * 64 + h * 16);
        uint4 a0 = vp[0], a1 = vp[1];
        float kk = fp8_to_f32(K0[(size_t)s * 64 + lane]);
        kacc += kk;
        _Float16 kh = (_Float16)kk;
        h2 k2 = {kh, kh};
        const unsigned int aw[8] = {a0.x, a0.y, a0.z, a0.w, a1.x, a1.y, a1.z, a1.w};
        #pragma unroll
        for (int j = 0; j < 8; ++j)
            u16[j] += k2 * __builtin_bit_cast(h2, aw[j]);
    }
    float u[16];
    #pragma unroll
    for (int j = 0; j < 8; ++j) { u[2 * j] = (float)u16[j].x; u[2 * j + 1] = (float)u16[j].y; }
    store_m_row(M1, SK1, node, lane, u, kacc);
    float qd = Q[(size_t)node * 64 + lane];
    #pragma unroll
    for (int j = 0; j < 16; ++j) u[j] *= qd;
    reduce_scatter16(u, lane & 15);
    float g = gh / den16(qd, kacc);
    hidden[(size_t)node * 64 + lane] += g * u[0];
}

// ---------------- hops 2/3: fp4 M gather (round-9 structure) ----------------
template<bool STORE>
__global__ __launch_bounds__(256) void hop23_all(
    const float* __restrict__ Q, const uint2* __restrict__ Mprev,
    const unsigned short* __restrict__ SKprev,
    const int* __restrict__ offsets, const int* __restrict__ csr,
    const float* __restrict__ temp, const float* __restrict__ hopwise,
    uint2* __restrict__ Mnext, unsigned short* __restrict__ SKnext,
    float* __restrict__ hidden, int N, int hop)
{
    int lane = threadIdx.x & 63;
    int node = blockIdx.x * 4 + (threadIdx.x >> 6);
    if (node >= N) return;
    float gh = gamma_for(temp, hopwise, lane >> 4, hop);
    const uint2* Mb = Mprev + lane;
    const unsigned short* SKb = SKprev + lane;
    float u[16];
    #pragma unroll
    for (int j = 0; j < 16; ++j) u[j] = 0.f;
    float kacc = 0.f;
    int beg = offsets[node], end = offsets[node + 1];
    int t = beg;
    for (; t + 3 < end; t += 4) {
        int s0 = csr[t], s1 = csr[t + 1], s2 = csr[t + 2], s3 = csr[t + 3];
        uint2 w0 = Mb[(size_t)s0 * 64];
        uint2 w1 = Mb[(size_t)s1 * 64];
        uint2 w2 = Mb[(size_t)s2 * 64];
        uint2 w3 = Mb[(size_t)s3 * 64];
        f2 sk0 = fp8x2_to_f32(SKb[(size_t)s0 * 64]);
        f2 sk1 = fp8x2_to_f32(SKb[(size_t)s1 * 64]);
        f2 sk2 = fp8x2_to_f32(SKb[(size_t)s2 * 64]);
        f2 sk3 = fp8x2_to_f32(SKb[(size_t)s3 * 64]);
        kacc += (sk0.y + sk1.y) + (sk2.y + sk3.y);
        float v[16];
        fp4x16_dec(w0, v);
        #pragma unroll
        for (int j = 0; j < 16; ++j) u[j] = fmaf(sk0.x, v[j], u[j]);
        fp4x16_dec(w1, v);
        #pragma unroll
        for (int j = 0; j < 16; ++j) u[j] = fmaf(sk1.x, v[j], u[j]);
        fp4x16_dec(w2, v);
        #pragma unroll
        for (int j = 0; j < 16; ++j) u[j] = fmaf(sk2.x, v[j], u[j]);
        fp4x16_dec(w3, v);
        #pragma unroll
        for (int j = 0; j < 16; ++j) u[j] = fmaf(sk3.x, v[j], u[j]);
    }
    for (; t < end; ++t) {
        int sn = csr[t];
        uint2 w = Mb[(size_t)sn * 64];
        f2 sk = fp8x2_to_f32(SKb[(size_t)sn * 64]);
        kacc += sk.y;
        float v[16];
        fp4x16_dec(w, v);
        #pragma unroll
        for (int j = 0; j < 16; ++j) u[j] = fmaf(sk.x, v[j], u[j]);
    }
    if (STORE) store_m_row(Mnext, SKnext, node, lane, u, kacc);
    float qd = Q[(size_t)node * 64 + lane];
    #pragma unroll
    for (int j = 0; j < 16; ++j) u[j] *= qd;
    reduce_scatter16(u, lane & 15);
    float g = gh / den16(qd, kacc);
    hidden[(size_t)node * 64 + lane] += g * u[0];
}

// ---------------- output projection ----------------
__global__ __launch_bounds__(256) void out_kernel(
    const float* __restrict__ hidden, const float* __restrict__ Wo,
    const float* __restrict__ bo, float* __restrict__ out, int N)
{
    __shared__ float wo[HID * CC];
    for (int i = threadIdx.x; i < HID * CC; i += 256) wo[i] = Wo[i];
    __syncthreads();
    int idx = blockIdx.x * 256 + threadIdx.x;
    int n = idx >> 4, c = idx & 15;
    if (n >= N) return;
    float acc = bo[c];
    const float4* hp4 = (const float4*)(hidden + (size_t)n * HID);
    #pragma unroll
    for (int j4 = 0; j4 < 16; ++j4) {
        float4 hv = hp4[j4];
        acc += hv.x * wo[(4 * j4 + 0) * CC + c] + hv.y * wo[(4 * j4 + 1) * CC + c]
             + hv.z * wo[(4 * j4 + 2) * CC + c] + hv.w * wo[(4 * j4 + 3) * CC + c];
    }
    out[(size_t)n * CC + c] = acc;
}

extern "C" void kernel_launch(void* const* d_in, const int* in_sizes, int n_in,
                              void* d_out, int out_size, void* d_ws, size_t ws_size,
                              hipStream_t stream) {
    const float* x       = (const float*)d_in[0];
    const int*   ei      = (const int*)  d_in[1];
    const float* Wi      = (const float*)d_in[2];
    const float* bi      = (const float*)d_in[3];
    const float* Wq      = (const float*)d_in[4];
    const float* bq      = (const float*)d_in[5];
    const float* Wk      = (const float*)d_in[6];
    const float* bk      = (const float*)d_in[7];
    const float* Wv      = (const float*)d_in[8];
    const float* bv      = (const float*)d_in[9];
    const float* Wo      = (const float*)d_in[10];
    const float* bo      = (const float*)d_in[11];
    const float* hopwise = (const float*)d_in[12];
    const float* temp    = (const float*)d_in[13];

    const int N = in_sizes[0] / F_IN;
    const int E = in_sizes[1] / 2;

    char* ws = (char*)d_ws;
    size_t off = 0;
    auto take = [&](size_t bytes) -> char* {
        char* p = ws + off;
        off += (bytes + 255) & ~(size_t)255;
        return p;
    };
    float*          Q      = (float*)take((size_t)N * 64 * 4);
    _Float16*       Vh     = (_Float16*)take((size_t)N * 64 * 2);
    float*          hidden = (float*)take((size_t)N * 64 * 4);
    unsigned char*  K0     = (unsigned char*)take((size_t)N * 64);
    unsigned short* SK1    = (unsigned short*)take((size_t)N * 64 * 2);
    unsigned short* SK2    = (unsigned short*)take((size_t)N * 64 * 2);
    int*            degcur = (int*)take((size_t)2 * N * 4);   // deg | cursor
    int*            offs   = (int*)take((size_t)(N + 1) * 4);
    int*            csr    = (int*)take((size_t)E * 4);
    int             nb     = (N + 4095) / 4096;
    int*            bsum   = (int*)take((size_t)nb * 4);
    uint2*          M1     = (uint2*)take((size_t)N * 512);
    uint2*          M2     = (uint2*)take((size_t)N * 512);

    int* deg    = degcur;
    int* cursor = degcur + N;

    hipMemsetAsync(degcur, 0, (size_t)2 * N * 4, stream);

    int eb = (E + 255) / 256;
    int qb = (N + 63) / 64;
    // fused: qkv (qb blocks) + degree count (eb blocks)
    qkv_count<<<qb + eb, 256, 0, stream>>>(x, Wi, bi, Wq, bq, Wk, bk, Wv, bv,
                                           temp, Q, K0, Vh, hidden,
                                           ei, deg, E, qb, N);
    scan_a<<<nb, 1024, 0, stream>>>(deg, offs, bsum, N);
    scan_c<<<(N + 255) / 256, 256, 0, stream>>>(offs, bsum, nb, N);
    scatter_kernel<<<eb, 256, 0, stream>>>(ei, offs, cursor, csr, E);

    int nb4 = (N + 3) / 4;
    hop1_all<<<nb4, 256, 0, stream>>>(Q, K0, Vh, offs, csr, temp, hopwise,
                                      M1, SK1, hidden, N);
    hop23_all<true ><<<nb4, 256, 0, stream>>>(Q, M1, SK1, offs, csr, temp, hopwise,
                                              M2, SK2, hidden, N, 2);
    hop23_all<false><<<nb4, 256, 0, stream>>>(Q, M2, SK2, offs, csr, temp, hopwise,
                                              (uint2*)nullptr, (unsigned short*)nullptr,
                                              hidden, N, 3);

    int ob = (N * CC + 255) / 256;
    out_kernel<<<ob, 256, 0, stream>>>(hidden, Wo, bo, (float*)d_out, N);
}